// Round 6
// baseline (55.046 us; speedup 1.0000x reference)
//
#include <hip/hip_runtime.h>
#include <hip/hip_bf16.h>

// TT/MPO matvec on MFMA (bf16 in / f32 accum), round 6.
//   S1: T1[(o1l,i3)][(i2,k1)] = c0m x v        (per o1, K=16 pad 32)
//   S2: T2[(o1l,o2)][(i3,k2)] = c1m x T1       (M tiled by o2, K=(i2,k1))
//   S3: out[b,o1,o2,o3]       = c2m x T2       (wave w<4 owns o1l=w)
// Round-5 lesson: occupancy 18%->35% changed nothing -> latency/barrier structure
// is the limiter, not wave count. So: 1 block/CU (96 KB LDS), VGPR ceiling 256,
// T2 double-buffered (barriers 3->2 per nc), all L2 frag streams prefetched into
// registers at nc-loop top (S2 becomes pure LDS+MFMA), S3 dual accumulator.
// Round-2 lesson (spills) is void at 2 waves/SIMD: 256 VGPR budget.

typedef short bf16x8 __attribute__((ext_vector_type(8)));
typedef float f32x4 __attribute__((ext_vector_type(4)));

#define WS_A1_OFF 0        // c1 frags: 16 o2 x 8 ks x 64 lanes x 16B = 131072 B
#define WS_A0_OFF 131072   // c0 frags: 16 o1 x 64 lanes x 16B       = 16384 B
#define WS_A2_OFF 147456   // c2 frags:  8 ks x 64 lanes x 16B       = 8192 B
#define WS_NEEDED 155648

__device__ __forceinline__ unsigned short f2bf(float f) {
    union { float f; unsigned int u; } x; x.f = f;
    unsigned int u = x.u;
    u += 0x7fffu + ((u >> 16) & 1u);   // RNE
    return (unsigned short)(u >> 16);
}

__device__ __forceinline__ unsigned int pk_bf16(float lo, float hi) {
    __hip_bfloat162 h = __float22bfloat162_rn(make_float2(lo, hi));  // RNE, x=lo -> [15:0]
    unsigned int r;
    __builtin_memcpy(&r, &h, 4);
    return r;
}

// ---------------- repack: c0/c1/c2 -> bf16 A-fragment layout in ws ----------------
// k-dim orderings: S2 kappa=(i2,k1): i2=k>>4, k1=k&15.  S3 kappa2=(i3,k2): i3=k>>4, k2=k&15.
__global__ void tt_repack(const float* __restrict__ c0,
                          const float* __restrict__ c1,
                          const float* __restrict__ c2,
                          unsigned short* __restrict__ ws) {
    int idx = blockIdx.x * 256 + threadIdx.x;
    if (idx < 8192) {                      // A1 (c1): frag (o2, ks, lane); A-row m = k2
        int o2 = idx >> 9, ks = (idx >> 6) & 7, l = idx & 63;
        int k2 = l & 15;
        unsigned short* dst = ws + ((size_t)(o2 * 8 + ks) * 64 + l) * 8;
        #pragma unroll
        for (int j = 0; j < 8; ++j) {
            int k = ks * 32 + ((l >> 4) * 8) + j;      // kappa = (i2,k1)
            dst[j] = f2bf(c1[(k & 15) * 4096 + o2 * 256 + (k >> 4) * 16 + k2]);
        }
    } else if (idx < 9216) {               // A0 (c0): frag (o1, lane); A-row m = k1; K=16 pad
        int t = idx - 8192;
        int o1 = t >> 6, l = t & 63;
        unsigned short* dst = ws + WS_A0_OFF / 2 + ((size_t)o1 * 64 + l) * 8;
        #pragma unroll
        for (int j = 0; j < 8; ++j) {
            int k = ((l >> 4) * 8) + j;                // i1 (or pad)
            float v = (l < 32) ? c0[o1 * 256 + k * 16 + (l & 15)] : 0.f;
            dst[j] = f2bf(v);
        }
    } else if (idx < 9728) {               // A2 (c2): frag (ks, lane); A-row m = o3
        int t = idx - 9216;
        int ks = t >> 6, l = t & 63;
        unsigned short* dst = ws + WS_A2_OFF / 2 + ((size_t)ks * 64 + l) * 8;
        #pragma unroll
        for (int j = 0; j < 8; ++j) {
            int k = ks * 32 + ((l >> 4) * 8) + j;      // kappa2 = (i3,k2)
            dst[j] = f2bf(c2[(k & 15) * 256 + (l & 15) * 16 + (k >> 4)]);
        }
    }
}

// ---------------- main kernel: 512 threads = 8 waves, 1 block/CU ----------------
template <bool PACKED>
__global__ __launch_bounds__(512, 2) void tt_main(
    const float* __restrict__ vg, const float* __restrict__ c0,
    const float* __restrict__ c1, const float* __restrict__ c2,
    const unsigned short* __restrict__ ws, float* __restrict__ outg)
{
    __shared__ unsigned short T1[16384];    // [n=(o1l,i3) 64][k=(i2,k1) 256], byte ^ ((n&7)<<4)
    __shared__ unsigned short T2[2][16384]; // ping-pong per nc; [n=(o1l,o2)][k=(i3,k2)], same swz

    const int b   = blockIdx.x;
    const int t   = threadIdx.x;
    const int w   = t >> 6;        // wave 0..7
    const int l   = t & 63;
    const int l15 = l & 15;
    const int lg  = l >> 4;

    // ---- preload: v B-frags (this wave's 2 i2 values) and c2 A-frags ----
    bf16x8 fb0[2];
    {
        const float* vb = vg + (size_t)b * 4096;
        #pragma unroll
        for (int nt = 0; nt < 2; ++nt) {
            bf16x8 f = {0, 0, 0, 0, 0, 0, 0, 0};
            if (l < 32) {
                int i2 = 2 * w + nt;
                const float* p = vb + (lg * 8) * 256 + i2 * 16 + l15;
                #pragma unroll
                for (int j = 0; j < 8; ++j) f[j] = (short)f2bf(p[j * 256]);
            }
            fb0[nt] = f;
        }
    }
    bf16x8 fa2[8];
    if constexpr (PACKED) {
        #pragma unroll
        for (int ks = 0; ks < 8; ++ks)
            fa2[ks] = *(const bf16x8*)(ws + WS_A2_OFF / 2 + ((size_t)ks * 64 + l) * 8);
    } else {
        for (int ks = 0; ks < 8; ++ks) {
            bf16x8 f;
            for (int j = 0; j < 8; ++j) {
                int k = ks * 32 + lg * 8 + j;
                f[j] = (short)f2bf(c2[(k & 15) * 256 + l15 * 16 + (k >> 4)]);
            }
            fa2[ks] = f;
        }
    }

    // per-thread lane slot in the c1 frag table; frag (o2,ks) at +(o2*8+ks)*512 shorts
    const unsigned short* a1p = PACKED ? (ws + (size_t)l * 8) : nullptr;

    for (int nc = 0; nc < 4; ++nc) {       // o1 chunk: o1 = nc*4 .. nc*4+3
        unsigned short* T2c = T2[nc & 1];

        // ---- prefetch this nc's streamed frags into registers (issue before bar1;
        //      latency hides under S1 + barrier; 2 waves/SIMD -> 256 VGPR budget) ----
        bf16x8 fa1p[16];   // c1 frags: [rt*8+ks] for o2 = 2w+rt
        bf16x8 fa0p[4];    // c0 frags for o1 = nc*4+mtl
        if constexpr (PACKED) {
            #pragma unroll
            for (int ks = 0; ks < 8; ++ks) {
                fa1p[ks]     = *(const bf16x8*)(a1p + ((2 * w + 0) * 8 + ks) * 512);
                fa1p[8 + ks] = *(const bf16x8*)(a1p + ((2 * w + 1) * 8 + ks) * 512);
            }
            #pragma unroll
            for (int mtl = 0; mtl < 4; ++mtl)
                fa0p[mtl] = *(const bf16x8*)(ws + WS_A0_OFF / 2 +
                                             ((size_t)(nc * 4 + mtl) * 64 + l) * 8);
        } else {
            for (int rt = 0; rt < 2; ++rt)
                for (int ks = 0; ks < 8; ++ks) {
                    int o2 = 2 * w + rt;
                    bf16x8 f;
                    for (int j = 0; j < 8; ++j) {
                        int k = ks * 32 + lg * 8 + j;
                        f[j] = (short)f2bf(c1[(k & 15) * 4096 + o2 * 256 + (k >> 4) * 16 + l15]);
                    }
                    fa1p[rt * 8 + ks] = f;
                }
            for (int mtl = 0; mtl < 4; ++mtl) {
                bf16x8 f = {0, 0, 0, 0, 0, 0, 0, 0};
                if (l < 32) {
                    for (int j = 0; j < 8; ++j)
                        f[j] = (short)f2bf(c0[(nc * 4 + mtl) * 256 + (lg * 8 + j) * 16 + l15]);
                }
                fa0p[mtl] = f;
            }
        }

        // ---------- S1: T1 rows (o1l,i3), k=(i2,k1); wave covers i2 = 2w,2w+1 ----------
        #pragma unroll
        for (int mtl = 0; mtl < 4; ++mtl) {
            #pragma unroll
            for (int nt = 0; nt < 2; ++nt) {
                f32x4 z = {0.f, 0.f, 0.f, 0.f};
                f32x4 d = __builtin_amdgcn_mfma_f32_16x16x32_bf16(fa0p[mtl], fb0[nt], z, 0, 0, 0);
                // D: row=k1=lg*4+r, col=i3=l15; this tile: i2 = 2w+nt
                const int i2 = 2 * w + nt;
                const int n  = mtl * 16 + l15;
                int byte = (n * 512 + (i2 * 16 + lg * 4) * 2) ^ ((l15 & 7) << 4);
                uint2 wv;
                wv.x = pk_bf16(d[0], d[1]);
                wv.y = pk_bf16(d[2], d[3]);
                *(uint2*)((char*)T1 + byte) = wv;   // 4 consecutive k1 -> one b64
            }
        }
        __syncthreads();   // bar1: T1 complete

        // ---------- S2: T2 = c1m x T1; wave w owns o2 = 2w, 2w+1; pure LDS+MFMA ----------
        {
            f32x4 acc[2][4];
            #pragma unroll
            for (int rt = 0; rt < 2; ++rt)
                #pragma unroll
                for (int nt = 0; nt < 4; ++nt) acc[rt][nt] = (f32x4){0.f, 0.f, 0.f, 0.f};

            #pragma unroll
            for (int ks = 0; ks < 8; ++ks) {
                #pragma unroll
                for (int nt = 0; nt < 4; ++nt) {
                    int byte = ((nt * 16 + l15) * 512 + (ks * 32 + lg * 8) * 2) ^ ((l15 & 7) << 4);
                    bf16x8 fb = *(const bf16x8*)((char*)T1 + byte);
                    acc[0][nt] = __builtin_amdgcn_mfma_f32_16x16x32_bf16(fa1p[ks],     fb, acc[0][nt], 0, 0, 0);
                    acc[1][nt] = __builtin_amdgcn_mfma_f32_16x16x32_bf16(fa1p[8 + ks], fb, acc[1][nt], 0, 0, 0);
                }
            }
            // flush: D row=k2=lg*4+r, col=(o1l=nt, i3=l15); T2 k=(i3,k2) -> r consecutive
            #pragma unroll
            for (int rt = 0; rt < 2; ++rt) {
                const int o2 = 2 * w + rt;
                #pragma unroll
                for (int nt = 0; nt < 4; ++nt) {
                    int byte = ((nt * 16 + o2) * 512 + (l15 * 16 + lg * 4) * 2) ^ ((o2 & 7) << 4);
                    uint2 wv;
                    wv.x = pk_bf16(acc[rt][nt][0], acc[rt][nt][1]);
                    wv.y = pk_bf16(acc[rt][nt][2], acc[rt][nt][3]);
                    *(uint2*)((char*)T2c + byte) = wv;
                }
            }
        }
        __syncthreads();   // bar2: T2c complete; also licenses next nc's T1 overwrite

        // ---------- S3: waves 0..3 own o1l = w; dual accumulator (halve MFMA chain) ----------
        if (w < 4) {
            f32x4 a3a = {0.f, 0.f, 0.f, 0.f};
            f32x4 a3b = {0.f, 0.f, 0.f, 0.f};
            #pragma unroll
            for (int ks = 0; ks < 8; ks += 2) {
                int byte0 = ((w * 16 + l15) * 512 + ((ks + 0) * 32 + lg * 8) * 2) ^ ((l15 & 7) << 4);
                int byte1 = ((w * 16 + l15) * 512 + ((ks + 1) * 32 + lg * 8) * 2) ^ ((l15 & 7) << 4);
                bf16x8 fbA = *(const bf16x8*)((char*)T2c + byte0);  // n=o2=l15, k=(i3,k2)
                bf16x8 fbB = *(const bf16x8*)((char*)T2c + byte1);
                a3a = __builtin_amdgcn_mfma_f32_16x16x32_bf16(fa2[ks],     fbA, a3a, 0, 0, 0);
                a3b = __builtin_amdgcn_mfma_f32_16x16x32_bf16(fa2[ks + 1], fbB, a3b, 0, 0, 0);
            }
            f32x4 acc3 = a3a + a3b;
            // D: row=o3=lg*4+r, col=o2=l15
            float* ob = outg + (size_t)b * 4096;
            *(f32x4*)(ob + (nc * 4 + w) * 256 + l15 * 16 + lg * 4) = acc3;
        }
        // no barrier: T2 ping-pong covers reuse; T1 overwrite guarded by bar2
    }
}

extern "C" void kernel_launch(void* const* d_in, const int* in_sizes, int n_in,
                              void* d_out, int out_size, void* d_ws, size_t ws_size,
                              hipStream_t stream) {
    const float* vg  = (const float*)d_in[0];
    const float* c0g = (const float*)d_in[1];
    const float* c1g = (const float*)d_in[2];
    const float* c2g = (const float*)d_in[3];
    float* outg = (float*)d_out;

    const int B = in_sizes[0] / 4096;
    const bool packed = (ws_size >= (size_t)WS_NEEDED) && (d_ws != nullptr);

    if (packed) {
        tt_repack<<<dim3(38), dim3(256), 0, stream>>>(c0g, c1g, c2g, (unsigned short*)d_ws);
        tt_main<true><<<dim3(B), dim3(512), 0, stream>>>(
            vg, c0g, c1g, c2g, (const unsigned short*)d_ws, outg);
    } else {
        tt_main<false><<<dim3(B), dim3(512), 0, stream>>>(
            vg, c0g, c1g, c2g, nullptr, outg);
    }
}